// Round 6
// baseline (922.875 us; speedup 1.0000x reference)
//
#include <hip/hip_runtime.h>
#include <hip/hip_bf16.h>
#include <cstdint>
#include <cstddef>

typedef __attribute__((ext_vector_type(8))) short short8;
typedef __attribute__((ext_vector_type(4))) short short4_;
typedef __attribute__((ext_vector_type(4))) float floatx4;
typedef __attribute__((ext_vector_type(4))) unsigned short ushort4_;

#define MFMA16(a, b, c) __builtin_amdgcn_mfma_f32_16x16x32_bf16((a), (b), (c), 0, 0, 0)

__device__ __forceinline__ unsigned short f2bf(float f) {
  __hip_bfloat16 h = __float2bfloat16(f);
  return *reinterpret_cast<unsigned short*>(&h);
}

__device__ __forceinline__ void gl_lds16(const void* g, void* lds) {
  __builtin_amdgcn_global_load_lds(
      (const __attribute__((address_space(1))) void*)g,
      (__attribute__((address_space(3))) void*)lds, 16, 0, 0);
}

// ---------------------------------------------------------------- fused cast kernel
// 32768 blocks: [0,16384) -> x (16.7M), then 4 x 4096 blocks for the weights.
__global__ void cast5_f32_bf16(const float* __restrict__ x, const float* __restrict__ wq,
                               const float* __restrict__ wk, const float* __restrict__ wv,
                               const float* __restrict__ wo,
                               __hip_bfloat16* __restrict__ xb, __hip_bfloat16* __restrict__ wqb,
                               __hip_bfloat16* __restrict__ wkb, __hip_bfloat16* __restrict__ wvb,
                               __hip_bfloat16* __restrict__ wob) {
  const int bid = blockIdx.x;
  const float* src;
  __hip_bfloat16* dst;
  int base;
  if (bid < 16384)      { src = x;  dst = xb;  base = bid; }
  else if (bid < 20480) { src = wq; dst = wqb; base = bid - 16384; }
  else if (bid < 24576) { src = wk; dst = wkb; base = bid - 20480; }
  else if (bid < 28672) { src = wv; dst = wvb; base = bid - 24576; }
  else                  { src = wo; dst = wob; base = bid - 28672; }
  const int i = base * 1024 + threadIdx.x * 4;
  const float4 v = *reinterpret_cast<const float4*>(src + i);
  ushort4_ o = { f2bf(v.x), f2bf(v.y), f2bf(v.z), f2bf(v.w) };
  *reinterpret_cast<ushort4_*>(dst + i) = o;
}

// ---------------------------------------------------------------- GEMM v2: 256x256 tile, BK=32
// 8 waves (2Mx4N), 4-slot LDS ring, counted-vmcnt prefetch (distance 3).
template <int MODE>
__global__ __launch_bounds__(512, 2)
void gemm256(const __hip_bfloat16* __restrict__ Ap, const __hip_bfloat16* __restrict__ Bp,
             const float* __restrict__ bias, void* __restrict__ Cout,
             int M, int N, int K) {
  __shared__ __align__(16) __hip_bfloat16 SA[4][256 * 32];
  __shared__ __align__(16) __hip_bfloat16 SB[4][256 * 32];

  const int tid = threadIdx.x;
  const int wid = tid >> 6, lane = tid & 63;
  const int wr = wid >> 2, wc = wid & 3;
  const int g = lane >> 4, c16 = lane & 15;

  const int swzb = (blockIdx.x & 7) * 32 + (blockIdx.x >> 3);
  const int bm = swzb >> 3, bn = swzb & 7;

  const int srow = lane >> 2;
  const int slog = (lane & 3) ^ ((lane >> 3) & 3);
  const int swz = c16 * 32 + (g ^ ((c16 >> 1) & 3)) * 8;

  floatx4 acc[8][4] = {};

  auto stage = [&](int kt) {
    const int kb = kt * 32;
    const int slot = kt & 3;
#pragma unroll
    for (int i = 0; i < 2; ++i) {
      const int rbase = i * 128 + wid * 16;
      gl_lds16(Ap + (size_t)(bm * 256 + rbase + srow) * K + kb + slog * 8,
               SA[slot] + rbase * 32);
      gl_lds16(Bp + (size_t)(bn * 256 + rbase + srow) * K + kb + slog * 8,
               SB[slot] + rbase * 32);
    }
  };

  auto compute = [&](int slot) {
    const __hip_bfloat16* sa = SA[slot];
    const __hip_bfloat16* sb = SB[slot];
    short8 af[8], bf[4];
#pragma unroll
    for (int m = 0; m < 8; ++m)
      af[m] = *reinterpret_cast<const short8*>(sa + wr * 4096 + m * 512 + swz);
#pragma unroll
    for (int n = 0; n < 4; ++n)
      bf[n] = *reinterpret_cast<const short8*>(sb + wc * 2048 + n * 512 + swz);
    __builtin_amdgcn_s_setprio(1);
#pragma unroll
    for (int m = 0; m < 8; ++m)
#pragma unroll
      for (int n = 0; n < 4; ++n)
        acc[m][n] = MFMA16(af[m], bf[n], acc[m][n]);
    __builtin_amdgcn_s_setprio(0);
  };

  const int nkt = K >> 5;
  stage(0); stage(1); stage(2);

  for (int kt = 0; kt < nkt - 3; ++kt) {
    asm volatile("s_waitcnt vmcnt(8)" ::: "memory");
    __builtin_amdgcn_s_barrier();
    stage(kt + 3);
    compute(kt & 3);
  }
  asm volatile("s_waitcnt vmcnt(8)" ::: "memory");
  __builtin_amdgcn_s_barrier();
  compute((nkt - 3) & 3);
  asm volatile("s_waitcnt vmcnt(4)" ::: "memory");
  __builtin_amdgcn_s_barrier();
  compute((nkt - 2) & 3);
  asm volatile("s_waitcnt vmcnt(0)" ::: "memory");
  __builtin_amdgcn_s_barrier();
  compute((nkt - 1) & 3);

#pragma unroll
  for (int n = 0; n < 4; ++n) {
    const int colg = bn * 256 + wc * 64 + n * 16 + c16;
    const float bv = bias[colg];
#pragma unroll
    for (int m = 0; m < 8; ++m) {
      const int rowg = bm * 256 + wr * 128 + m * 16 + g * 4;
      if (MODE == 0) {
        __hip_bfloat16* C = (__hip_bfloat16*)Cout;
#pragma unroll
        for (int j = 0; j < 4; ++j)
          C[(size_t)(rowg + j) * N + colg] = __float2bfloat16(acc[m][n][j] + bv);
      } else if (MODE == 1) {
        __hip_bfloat16* C = (__hip_bfloat16*)Cout;
        const int bb = rowg >> 11, t0 = rowg & 2047;
        ushort4_ pk = { f2bf(acc[m][n][0] + bv), f2bf(acc[m][n][1] + bv),
                        f2bf(acc[m][n][2] + bv), f2bf(acc[m][n][3] + bv) };
        *reinterpret_cast<ushort4_*>(C + ((size_t)bb * 2048 + colg) * 2048 + t0) = pk;
      } else {
        float* C = (float*)Cout;
#pragma unroll
        for (int j = 0; j < 4; ++j)
          C[(size_t)(rowg + j) * N + colg] = acc[m][n][j] + bv;
      }
    }
  }
}

// ---------------------------------------------------------------- flash attention v5 (causal)
// Swapped-operand (S^T/O^T, col=q=c16) + LDS 40960 B -> 4 blocks/CU:
// Ks[64][128] slot-XOR swizzled, Vs[128][64] slot-XOR, Pl[16][64]/wave (m-sequenced).
// Softmax in exp2 domain (v_exp_f32 direct). T13 defer-max, T14 prefetch, T5 setprio.
__global__ __launch_bounds__(256, 4)
void attn_fwd5(const __hip_bfloat16* __restrict__ Q, const __hip_bfloat16* __restrict__ K,
               const __hip_bfloat16* __restrict__ Vt, __hip_bfloat16* __restrict__ ctx) {
  constexpr int T = 2048, C = 2048, D = 128;
  __shared__ __align__(16) __hip_bfloat16 Ks[64 * 128];   // 16 KB, slot^(row&7)
  __shared__ __align__(16) __hip_bfloat16 Vs[128 * 64];   // 16 KB, slot^(row&7)
  __shared__ __align__(16) __hip_bfloat16 Pl[4][16 * 64]; //  8 KB, slot^c16, per-wave

  const int tid = threadIdx.x;
  const int w = tid >> 6, lane = tid & 63;
  const int g = lane >> 4, c16 = lane & 15;

  const int bid = blockIdx.x;
  const int swz = (bid & 7) * 128 + (bid >> 3);
  const int bh = swz >> 4, qb = 15 - (swz & 15);
  const int b = bh >> 4, h = bh & 15;
  const int wq = qb * 128 + w * 32;

  const __hip_bfloat16* Qh = Q + (size_t)b * T * C + h * D;
  const __hip_bfloat16* Kh = K + (size_t)b * T * C + h * D;
  const __hip_bfloat16* Vh = Vt + (size_t)bh * D * T;

  short8 qf[2][4];
#pragma unroll
  for (int m = 0; m < 2; ++m)
#pragma unroll
    for (int kk = 0; kk < 4; ++kk)
      qf[m][kk] = *reinterpret_cast<const short8*>(Qh + (size_t)(wq + m * 16 + c16) * C + kk * 32 + g * 8);

  floatx4 acc[2][8] = {};
  float mrow[2] = {-INFINITY, -INFINITY};
  float lrow[2] = {0.f, 0.f};

  const float scale2 = 0.12751744f;                 // (1/sqrt(128)) * log2(e)
  const int krow = tid >> 4;                        // K staging: 16 rows/pass
  const int kslot = (tid & 15) ^ (krow & 7);        // phys 16B slot (XOR by row)
  const int vrow = tid >> 3;
  const int vslot = (tid & 7) ^ (vrow & 7);
  const int vgcol = (tid & 7) * 8;
  const int kgcol = (tid & 15) * 8;

  short8 kr[4], vr[4];
  auto gloadK = [&](int kb) {
#pragma unroll
    for (int p = 0; p < 4; ++p)
      kr[p] = *reinterpret_cast<const short8*>(Kh + (size_t)(kb + p * 16 + krow) * C + kgcol);
  };
  auto gloadV = [&](int kb) {
#pragma unroll
    for (int p = 0; p < 4; ++p)
      vr[p] = *reinterpret_cast<const short8*>(Vh + (size_t)(p * 32 + vrow) * T + kb + vgcol);
  };

  __hip_bfloat16* Pq = Pl[w];
  const int nkt = qb * 2 + 2;
  gloadK(0);
  gloadV(0);

  for (int kt = 0; kt < nkt; ++kt) {
    const int kb = kt * 64;
    __syncthreads();
#pragma unroll
    for (int p = 0; p < 4; ++p)
      *reinterpret_cast<short8*>(&Ks[(p * 16 + krow) * 128 + kslot * 8]) = kr[p];
#pragma unroll
    for (int p = 0; p < 4; ++p)
      *reinterpret_cast<short8*>(&Vs[(p * 32 + vrow) * 64 + vslot * 8]) = vr[p];
    __syncthreads();

    const bool hasnext = (kt + 1 < nkt);
    const bool part = (kb <= wq + 31);
    if (hasnext) gloadK(kb + 64);

    short8 pb[2][2];
    if (part) {
      const bool needmask = (kb + 63 > wq);
      floatx4 s[2][4] = {};
      __builtin_amdgcn_s_setprio(1);
#pragma unroll
      for (int n = 0; n < 4; ++n)
#pragma unroll
        for (int kk = 0; kk < 4; ++kk) {
          short8 kf = *reinterpret_cast<const short8*>(
              &Ks[(n * 16 + c16) * 128 + (((kk * 4 + g) ^ (c16 & 7)) * 8)]);
          s[0][n] = MFMA16(kf, qf[0][kk], s[0][n]);
          s[1][n] = MFMA16(kf, qf[1][kk], s[1][n]);
        }
      __builtin_amdgcn_s_setprio(0);
      // ---- scale (exp2 domain) + mask + lane-local row max
      float vmax[2];
#pragma unroll
      for (int m = 0; m < 2; ++m) {
        const int q = wq + m * 16 + c16;
        float vm = -INFINITY;
#pragma unroll
        for (int n = 0; n < 4; ++n)
#pragma unroll
          for (int j = 0; j < 4; ++j) {
            float a = s[m][n][j] * scale2;
            if (needmask && (kb + n * 16 + g * 4 + j > q)) a = -INFINITY;
            s[m][n][j] = a;
            vm = fmaxf(vm, a);
          }
        vm = fmaxf(vm, __shfl_xor(vm, 16));
        vm = fmaxf(vm, __shfl_xor(vm, 32));
        vmax[m] = vm;
      }
      const float grow = fmaxf(vmax[0] - mrow[0], vmax[1] - mrow[1]);
      const bool nore = __all(grow <= 8.0f);
#pragma unroll
      for (int m = 0; m < 2; ++m) {
        const float mn = nore ? mrow[m] : fmaxf(mrow[m], vmax[m]);
        float rs = 0.f;
#pragma unroll
        for (int n = 0; n < 4; ++n) {
          float p0 = exp2f(s[m][n][0] - mn), p1 = exp2f(s[m][n][1] - mn);
          float p2 = exp2f(s[m][n][2] - mn), p3 = exp2f(s[m][n][3] - mn);
          rs += (p0 + p1) + (p2 + p3);
          ushort4_ pk = { f2bf(p0), f2bf(p1), f2bf(p2), f2bf(p3) };
          *reinterpret_cast<ushort4_*>(&Pq[c16 * 64 + (((4 * n + g) ^ c16) * 4)]) = pk;
        }
        rs += __shfl_xor(rs, 16);
        rs += __shfl_xor(rs, 32);
        if (nore) {
          lrow[m] += rs;
        } else {
          const float sc = exp2f(mrow[m] - mn);
          lrow[m] = lrow[m] * sc + rs;
          mrow[m] = mn;
#pragma unroll
          for (int dt = 0; dt < 8; ++dt)
#pragma unroll
            for (int j = 0; j < 4; ++j) acc[m][dt][j] *= sc;
        }
        // read this m's P fragments before m+1 overwrites the buffer (DS in-order per wave)
#pragma unroll
        for (int ks = 0; ks < 2; ++ks) {
          short4_ lo = *reinterpret_cast<const short4_*>(&Pq[c16 * 64 + (((8 * ks + 2 * g) ^ c16) * 4)]);
          short4_ hi = *reinterpret_cast<const short4_*>(&Pq[c16 * 64 + (((8 * ks + 2 * g + 1) ^ c16) * 4)]);
          short8 r;
          r[0] = lo[0]; r[1] = lo[1]; r[2] = lo[2]; r[3] = lo[3];
          r[4] = hi[0]; r[5] = hi[1]; r[6] = hi[2]; r[7] = hi[3];
          pb[m][ks] = r;
        }
      }
    }
    if (hasnext) gloadV(kb + 64);
    if (part) {
      __builtin_amdgcn_s_setprio(1);
#pragma unroll
      for (int dt = 0; dt < 8; ++dt)
#pragma unroll
        for (int ks = 0; ks < 2; ++ks) {
          const int pslot = ((ks * 4 + g) ^ (c16 & 7)) * 8;
          short8 vf = *reinterpret_cast<const short8*>(&Vs[(dt * 16 + c16) * 64 + pslot]);
          acc[0][dt] = MFMA16(vf, pb[0][ks], acc[0][dt]);
          acc[1][dt] = MFMA16(vf, pb[1][ks], acc[1][dt]);
        }
      __builtin_amdgcn_s_setprio(0);
    }
  }

#pragma unroll
  for (int m = 0; m < 2; ++m) {
    const float inv = 1.0f / lrow[m];
    const size_t row = (size_t)b * T + wq + m * 16 + c16;
#pragma unroll
    for (int dt = 0; dt < 8; ++dt) {
      ushort4_ o = { f2bf(acc[m][dt][0] * inv), f2bf(acc[m][dt][1] * inv),
                     f2bf(acc[m][dt][2] * inv), f2bf(acc[m][dt][3] * inv) };
      *reinterpret_cast<ushort4_*>(ctx + row * C + h * D + dt * 16 + g * 4) = o;
    }
  }
}

// ---------------------------------------------------------------- launch
extern "C" void kernel_launch(void* const* d_in, const int* in_sizes, int n_in,
                              void* d_out, int out_size, void* d_ws, size_t ws_size,
                              hipStream_t stream) {
  const float* x  = (const float*)d_in[0];
  const float* Wq = (const float*)d_in[1];
  const float* bq = (const float*)d_in[2];
  const float* Wk = (const float*)d_in[3];
  const float* bk = (const float*)d_in[4];
  const float* Wv = (const float*)d_in[5];
  const float* bv = (const float*)d_in[6];
  const float* Wo = (const float*)d_in[7];
  const float* bo = (const float*)d_in[8];

  const int M = 8192, N = 2048, K = 2048;
  const size_t MB = 1u << 20;
  char* ws = (char*)d_ws;
  __hip_bfloat16* xb  = (__hip_bfloat16*)(ws);
  __hip_bfloat16* wqb = (__hip_bfloat16*)(ws + 32 * MB);
  __hip_bfloat16* wkb = (__hip_bfloat16*)(ws + 40 * MB);
  __hip_bfloat16* wvb = (__hip_bfloat16*)(ws + 48 * MB);
  __hip_bfloat16* wob = (__hip_bfloat16*)(ws + 56 * MB);
  __hip_bfloat16* Qb  = (__hip_bfloat16*)(ws + 64 * MB);
  __hip_bfloat16* Kb  = (__hip_bfloat16*)(ws + 96 * MB);
  __hip_bfloat16* Vtb = (__hip_bfloat16*)(ws + 128 * MB);
  if (ws_size < 160 * MB) return;

  cast5_f32_bf16<<<32768, 256, 0, stream>>>(x, Wq, Wk, Wv, Wo, xb, wqb, wkb, wvb, wob);

  const dim3 gg((M / 256) * (N / 256));
  gemm256<0><<<gg, 512, 0, stream>>>(xb, wqb, bq, Qb, M, N, K);
  gemm256<0><<<gg, 512, 0, stream>>>(xb, wkb, bk, Kb, M, N, K);
  gemm256<1><<<gg, 512, 0, stream>>>(xb, wvb, bv, Vtb, M, N, K);

  attn_fwd5<<<64 * 16, 256, 0, stream>>>(Qb, Kb, Vtb, xb);

  gemm256<2><<<gg, 512, 0, stream>>>(xb, wob, bo, d_out, M, N, K);
}

// Round 7
// 548.079 us; speedup vs baseline: 1.6838x; 1.6838x over previous
//
#include <hip/hip_runtime.h>
#include <hip/hip_bf16.h>
#include <cstdint>
#include <cstddef>

typedef __attribute__((ext_vector_type(8))) short short8;
typedef __attribute__((ext_vector_type(4))) short short4_;
typedef __attribute__((ext_vector_type(4))) float floatx4;
typedef __attribute__((ext_vector_type(4))) unsigned short ushort4_;

#define MFMA16(a, b, c) __builtin_amdgcn_mfma_f32_16x16x32_bf16((a), (b), (c), 0, 0, 0)

__device__ __forceinline__ unsigned short f2bf(float f) {
  __hip_bfloat16 h = __float2bfloat16(f);
  return *reinterpret_cast<unsigned short*>(&h);
}

__device__ __forceinline__ void gl_lds16(const void* g, void* lds) {
  __builtin_amdgcn_global_load_lds(
      (const __attribute__((address_space(1))) void*)g,
      (__attribute__((address_space(3))) void*)lds, 16, 0, 0);
}

// ---------------------------------------------------------------- fused cast kernel
__global__ void cast5_f32_bf16(const float* __restrict__ x, const float* __restrict__ wq,
                               const float* __restrict__ wk, const float* __restrict__ wv,
                               const float* __restrict__ wo,
                               __hip_bfloat16* __restrict__ xb, __hip_bfloat16* __restrict__ wqb,
                               __hip_bfloat16* __restrict__ wkb, __hip_bfloat16* __restrict__ wvb,
                               __hip_bfloat16* __restrict__ wob) {
  const int bid = blockIdx.x;
  const float* src;
  __hip_bfloat16* dst;
  int base;
  if (bid < 16384)      { src = x;  dst = xb;  base = bid; }
  else if (bid < 20480) { src = wq; dst = wqb; base = bid - 16384; }
  else if (bid < 24576) { src = wk; dst = wkb; base = bid - 20480; }
  else if (bid < 28672) { src = wv; dst = wvb; base = bid - 24576; }
  else                  { src = wo; dst = wob; base = bid - 28672; }
  const int i = base * 1024 + threadIdx.x * 4;
  const float4 v = *reinterpret_cast<const float4*>(src + i);
  ushort4_ o = { f2bf(v.x), f2bf(v.y), f2bf(v.z), f2bf(v.w) };
  *reinterpret_cast<ushort4_*>(dst + i) = o;
}

// ---------------------------------------------------------------- GEMM: 256x256 tile, BK=32
// 8 waves (2Mx4N), 4-slot LDS ring, counted-vmcnt prefetch (distance 3).
// MODE 2: f32 out row-major (final proj).
// MODE 3: fused QKV. B = [6144][2048] (Wq|Wk|Wv rows), segment = colg>>11:
//         seg 0/1 -> bf16 row-major into Cout + seg*16M elems (Q, K);
//         seg 2   -> transposed per-batch Vt at Cout + 32M elems.
template <int MODE>
__global__ __launch_bounds__(512, 2)
void gemm256(const __hip_bfloat16* __restrict__ Ap, const __hip_bfloat16* __restrict__ Bp,
             const float* __restrict__ b0, const float* __restrict__ b1,
             const float* __restrict__ b2, void* __restrict__ Cout,
             int M, int N, int K) {
  __shared__ __align__(16) __hip_bfloat16 SA[4][256 * 32];
  __shared__ __align__(16) __hip_bfloat16 SB[4][256 * 32];

  const int tid = threadIdx.x;
  const int wid = tid >> 6, lane = tid & 63;
  const int wr = wid >> 2, wc = wid & 3;
  const int g = lane >> 4, c16 = lane & 15;

  // bijective XCD-chunked swizzle (gridDim.x % 8 == 0)
  const int nbn = N >> 8;
  const int cpx = gridDim.x >> 3;
  const int swzb = (blockIdx.x & 7) * cpx + (blockIdx.x >> 3);
  const int bm = swzb / nbn, bn = swzb % nbn;

  const int srow = lane >> 2;
  const int slog = (lane & 3) ^ ((lane >> 3) & 3);
  const int swz = c16 * 32 + (g ^ ((c16 >> 1) & 3)) * 8;

  floatx4 acc[8][4] = {};

  auto stage = [&](int kt) {
    const int kb = kt * 32;
    const int slot = kt & 3;
#pragma unroll
    for (int i = 0; i < 2; ++i) {
      const int rbase = i * 128 + wid * 16;
      gl_lds16(Ap + (size_t)(bm * 256 + rbase + srow) * K + kb + slog * 8,
               SA[slot] + rbase * 32);
      gl_lds16(Bp + (size_t)(bn * 256 + rbase + srow) * K + kb + slog * 8,
               SB[slot] + rbase * 32);
    }
  };

  auto compute = [&](int slot) {
    const __hip_bfloat16* sa = SA[slot];
    const __hip_bfloat16* sb = SB[slot];
    short8 af[8], bf[4];
#pragma unroll
    for (int m = 0; m < 8; ++m)
      af[m] = *reinterpret_cast<const short8*>(sa + wr * 4096 + m * 512 + swz);
#pragma unroll
    for (int n = 0; n < 4; ++n)
      bf[n] = *reinterpret_cast<const short8*>(sb + wc * 2048 + n * 512 + swz);
    __builtin_amdgcn_s_setprio(1);
#pragma unroll
    for (int m = 0; m < 8; ++m)
#pragma unroll
      for (int n = 0; n < 4; ++n)
        acc[m][n] = MFMA16(af[m], bf[n], acc[m][n]);
    __builtin_amdgcn_s_setprio(0);
  };

  const int nkt = K >> 5;
  stage(0); stage(1); stage(2);

  for (int kt = 0; kt < nkt - 3; ++kt) {
    asm volatile("s_waitcnt vmcnt(8)" ::: "memory");
    __builtin_amdgcn_s_barrier();
    stage(kt + 3);
    compute(kt & 3);
  }
  asm volatile("s_waitcnt vmcnt(8)" ::: "memory");
  __builtin_amdgcn_s_barrier();
  compute((nkt - 3) & 3);
  asm volatile("s_waitcnt vmcnt(4)" ::: "memory");
  __builtin_amdgcn_s_barrier();
  compute((nkt - 2) & 3);
  asm volatile("s_waitcnt vmcnt(0)" ::: "memory");
  __builtin_amdgcn_s_barrier();
  compute((nkt - 1) & 3);

#pragma unroll
  for (int n = 0; n < 4; ++n) {
    const int colg = bn * 256 + wc * 64 + n * 16 + c16;
    int seg = 0, colh = colg;
    float bv;
    if (MODE == 3) {
      seg = colg >> 11;            // block-uniform (segment boundaries at bn = 8, 16)
      colh = colg & 2047;
      bv = (seg == 0 ? b0 : (seg == 1 ? b1 : b2))[colh];
    } else {
      bv = b0[colg];
    }
#pragma unroll
    for (int m = 0; m < 8; ++m) {
      const int rowg = bm * 256 + wr * 128 + m * 16 + g * 4;
      if (MODE == 3) {
        if (seg < 2) {
          __hip_bfloat16* C = (__hip_bfloat16*)Cout + (size_t)seg * 16777216u;
#pragma unroll
          for (int j = 0; j < 4; ++j)
            C[(size_t)(rowg + j) * 2048 + colh] = __float2bfloat16(acc[m][n][j] + bv);
        } else {
          __hip_bfloat16* C = (__hip_bfloat16*)Cout + (size_t)2 * 16777216u;
          const int bb = rowg >> 11, t0 = rowg & 2047;
          ushort4_ pk = { f2bf(acc[m][n][0] + bv), f2bf(acc[m][n][1] + bv),
                          f2bf(acc[m][n][2] + bv), f2bf(acc[m][n][3] + bv) };
          *reinterpret_cast<ushort4_*>(C + ((size_t)bb * 2048 + colh) * 2048 + t0) = pk;
        }
      } else {
        float* C = (float*)Cout;
#pragma unroll
        for (int j = 0; j < 4; ++j)
          C[(size_t)(rowg + j) * N + colg] = acc[m][n][j] + bv;
      }
    }
  }
}

// ---------------------------------------------------------------- flash attention v4b (causal)
// Proven round-4 structure (LB(256,2), VGPR ~108) + exp2-domain softmax.
// Swapped-operand: QK^T as MFMA(K,Q) -> S^T (col=q=c16), PV as MFMA(V,P) -> O^T.
__global__ __launch_bounds__(256, 2)
void attn_fwd4(const __hip_bfloat16* __restrict__ Q, const __hip_bfloat16* __restrict__ K,
               const __hip_bfloat16* __restrict__ Vt, __hip_bfloat16* __restrict__ ctx) {
  constexpr int T = 2048, C = 2048, D = 128;
  __shared__ __align__(16) __hip_bfloat16 Ks[64][136];
  __shared__ __align__(16) __hip_bfloat16 Vs[128][64];
  __shared__ __align__(16) __hip_bfloat16 Pl[4][32][64];

  const int tid = threadIdx.x;
  const int w = tid >> 6, lane = tid & 63;
  const int g = lane >> 4, c16 = lane & 15;

  const int bid = blockIdx.x;
  const int swz = (bid & 7) * 128 + (bid >> 3);
  const int bh = swz >> 4, qb = 15 - (swz & 15);
  const int b = bh >> 4, h = bh & 15;
  const int wq = qb * 128 + w * 32;

  const __hip_bfloat16* Qh = Q + (size_t)b * T * C + h * D;
  const __hip_bfloat16* Kh = K + (size_t)b * T * C + h * D;
  const __hip_bfloat16* Vh = Vt + (size_t)bh * D * T;

  short8 qf[2][4];
#pragma unroll
  for (int m = 0; m < 2; ++m)
#pragma unroll
    for (int kk = 0; kk < 4; ++kk)
      qf[m][kk] = *reinterpret_cast<const short8*>(Qh + (size_t)(wq + m * 16 + c16) * C + kk * 32 + g * 8);

  floatx4 acc[2][8] = {};
  float mrow[2] = {-INFINITY, -INFINITY};
  float lrow[2] = {0.f, 0.f};

  const float scale2 = 0.12751744f;     // log2(e) / sqrt(128) -> exp2 domain
  const int krow = tid >> 4, kcol = (tid & 15) * 8;
  const int vrow = tid >> 3;
  const int vslot = (tid & 7) ^ (vrow & 7);
  const int vgcol = (tid & 7) * 8;

  short8 kr[4], vr[4];
  auto gloadK = [&](int kb) {
#pragma unroll
    for (int p = 0; p < 4; ++p)
      kr[p] = *reinterpret_cast<const short8*>(Kh + (size_t)(kb + p * 16 + krow) * C + kcol);
  };
  auto gloadV = [&](int kb) {
#pragma unroll
    for (int p = 0; p < 4; ++p)
      vr[p] = *reinterpret_cast<const short8*>(Vh + (size_t)(p * 32 + vrow) * T + kb + vgcol);
  };

  __hip_bfloat16 (*Pq)[64] = Pl[w];
  const int nkt = qb * 2 + 2;
  gloadK(0);
  gloadV(0);

  for (int kt = 0; kt < nkt; ++kt) {
    const int kb = kt * 64;
    __syncthreads();
#pragma unroll
    for (int p = 0; p < 4; ++p)
      *reinterpret_cast<short8*>(&Ks[p * 16 + krow][kcol]) = kr[p];
#pragma unroll
    for (int p = 0; p < 4; ++p)
      *reinterpret_cast<short8*>(&Vs[p * 32 + vrow][vslot * 8]) = vr[p];
    __syncthreads();

    const bool hasnext = (kt + 1 < nkt);
    const bool part = (kb <= wq + 31);
    if (hasnext) gloadK(kb + 64);

    if (part) {
      const bool needmask = (kb + 63 > wq);
      floatx4 s[2][4] = {};
      __builtin_amdgcn_s_setprio(1);
#pragma unroll
      for (int n = 0; n < 4; ++n)
#pragma unroll
        for (int kk = 0; kk < 4; ++kk) {
          short8 kf = *reinterpret_cast<const short8*>(&Ks[n * 16 + c16][kk * 32 + g * 8]);
          s[0][n] = MFMA16(kf, qf[0][kk], s[0][n]);
          s[1][n] = MFMA16(kf, qf[1][kk], s[1][n]);
        }
      __builtin_amdgcn_s_setprio(0);
      float vmax[2];
#pragma unroll
      for (int m = 0; m < 2; ++m) {
        const int q = wq + m * 16 + c16;
        float vm = -INFINITY;
#pragma unroll
        for (int n = 0; n < 4; ++n)
#pragma unroll
          for (int j = 0; j < 4; ++j) {
            float a = s[m][n][j] * scale2;
            if (needmask && (kb + n * 16 + g * 4 + j > q)) a = -INFINITY;
            s[m][n][j] = a;
            vm = fmaxf(vm, a);
          }
        vm = fmaxf(vm, __shfl_xor(vm, 16));
        vm = fmaxf(vm, __shfl_xor(vm, 32));
        vmax[m] = vm;
      }
      const float grow = fmaxf(vmax[0] - mrow[0], vmax[1] - mrow[1]);
      const bool nore = __all(grow <= 8.0f);
#pragma unroll
      for (int m = 0; m < 2; ++m) {
        const float mn = nore ? mrow[m] : fmaxf(mrow[m], vmax[m]);
        float rs = 0.f;
#pragma unroll
        for (int n = 0; n < 4; ++n) {
          float p0 = exp2f(s[m][n][0] - mn), p1 = exp2f(s[m][n][1] - mn);
          float p2 = exp2f(s[m][n][2] - mn), p3 = exp2f(s[m][n][3] - mn);
          rs += (p0 + p1) + (p2 + p3);
          ushort4_ pk = { f2bf(p0), f2bf(p1), f2bf(p2), f2bf(p3) };
          *reinterpret_cast<ushort4_*>(&Pq[m * 16 + c16][((4 * n + g) ^ c16) * 4]) = pk;
        }
        rs += __shfl_xor(rs, 16);
        rs += __shfl_xor(rs, 32);
        if (nore) {
          lrow[m] += rs;
        } else {
          const float sc = exp2f(mrow[m] - mn);
          lrow[m] = lrow[m] * sc + rs;
          mrow[m] = mn;
#pragma unroll
          for (int dt = 0; dt < 8; ++dt)
#pragma unroll
            for (int j = 0; j < 4; ++j) acc[m][dt][j] *= sc;
        }
      }
    }
    if (hasnext) gloadV(kb + 64);
    if (part) {
      short8 pb[2][2];
#pragma unroll
      for (int m = 0; m < 2; ++m)
#pragma unroll
        for (int ks = 0; ks < 2; ++ks) {
          short4_ lo = *reinterpret_cast<const short4_*>(&Pq[m * 16 + c16][((8 * ks + 2 * g) ^ c16) * 4]);
          short4_ hi = *reinterpret_cast<const short4_*>(&Pq[m * 16 + c16][((8 * ks + 2 * g + 1) ^ c16) * 4]);
          short8 r;
          r[0] = lo[0]; r[1] = lo[1]; r[2] = lo[2]; r[3] = lo[3];
          r[4] = hi[0]; r[5] = hi[1]; r[6] = hi[2]; r[7] = hi[3];
          pb[m][ks] = r;
        }
      __builtin_amdgcn_s_setprio(1);
#pragma unroll
      for (int dt = 0; dt < 8; ++dt)
#pragma unroll
        for (int ks = 0; ks < 2; ++ks) {
          const int pslot = ((ks * 4 + g) ^ (c16 & 7)) * 8;
          short8 vf = *reinterpret_cast<const short8*>(&Vs[dt * 16 + c16][pslot]);
          acc[0][dt] = MFMA16(vf, pb[0][ks], acc[0][dt]);
          acc[1][dt] = MFMA16(vf, pb[1][ks], acc[1][dt]);
        }
      __builtin_amdgcn_s_setprio(0);
    }
  }

#pragma unroll
  for (int m = 0; m < 2; ++m) {
    const float inv = 1.0f / lrow[m];
    const size_t row = (size_t)b * T + wq + m * 16 + c16;
#pragma unroll
    for (int dt = 0; dt < 8; ++dt) {
      ushort4_ o = { f2bf(acc[m][dt][0] * inv), f2bf(acc[m][dt][1] * inv),
                     f2bf(acc[m][dt][2] * inv), f2bf(acc[m][dt][3] * inv) };
      *reinterpret_cast<ushort4_*>(ctx + row * C + h * D + dt * 16 + g * 4) = o;
    }
  }
}

// ---------------------------------------------------------------- launch
extern "C" void kernel_launch(void* const* d_in, const int* in_sizes, int n_in,
                              void* d_out, int out_size, void* d_ws, size_t ws_size,
                              hipStream_t stream) {
  const float* x  = (const float*)d_in[0];
  const float* Wq = (const float*)d_in[1];
  const float* bq = (const float*)d_in[2];
  const float* Wk = (const float*)d_in[3];
  const float* bk = (const float*)d_in[4];
  const float* Wv = (const float*)d_in[5];
  const float* bv = (const float*)d_in[6];
  const float* Wo = (const float*)d_in[7];
  const float* bo = (const float*)d_in[8];

  const int M = 8192, K = 2048;
  const size_t MB = 1u << 20;
  char* ws = (char*)d_ws;
  // xb 32M | wqkv 24M (contiguous: wq|wk|wv) | wo 8M | Q 32M | K 32M | Vt 32M = 160 MiB
  __hip_bfloat16* xb   = (__hip_bfloat16*)(ws);
  __hip_bfloat16* wqkv = (__hip_bfloat16*)(ws + 32 * MB);
  __hip_bfloat16* wkb  = (__hip_bfloat16*)(ws + 40 * MB);
  __hip_bfloat16* wvb  = (__hip_bfloat16*)(ws + 48 * MB);
  __hip_bfloat16* wob  = (__hip_bfloat16*)(ws + 56 * MB);
  __hip_bfloat16* Qb   = (__hip_bfloat16*)(ws + 64 * MB);
  __hip_bfloat16* Kb   = (__hip_bfloat16*)(ws + 96 * MB);
  __hip_bfloat16* Vtb  = (__hip_bfloat16*)(ws + 128 * MB);
  if (ws_size < 160 * MB) return;

  cast5_f32_bf16<<<32768, 256, 0, stream>>>(x, Wq, Wk, Wv, Wo, xb, wqkv, wkb, wvb, wob);

  // fused QKV projection: one dispatch, B = [6144][2048], out = Qb|Kb|Vtb region
  gemm256<3><<<dim3((M / 256) * (6144 / 256)), 512, 0, stream>>>(
      xb, wqkv, bq, bk, bv, Qb, M, 6144, K);

  attn_fwd4<<<64 * 16, 256, 0, stream>>>(Qb, Kb, Vtb, xb);

  gemm256<2><<<dim3((M / 256) * (2048 / 256)), 512, 0, stream>>>(
      xb, wob, bo, bo, bo, d_out, M, 2048, K);
}

// Round 9
// 500.743 us; speedup vs baseline: 1.8430x; 1.0945x over previous
//
#include <hip/hip_runtime.h>
#include <hip/hip_bf16.h>
#include <cstdint>
#include <cstddef>

typedef __attribute__((ext_vector_type(8))) short short8;
typedef __attribute__((ext_vector_type(4))) short short4_;
typedef __attribute__((ext_vector_type(4))) float floatx4;
typedef __attribute__((ext_vector_type(4))) unsigned short ushort4_;

#define MFMA16(a, b, c) __builtin_amdgcn_mfma_f32_16x16x32_bf16((a), (b), (c), 0, 0, 0)

__device__ __forceinline__ unsigned short f2bf(float f) {
  __hip_bfloat16 h = __float2bfloat16(f);
  return *reinterpret_cast<unsigned short*>(&h);
}

__device__ __forceinline__ void gl_lds16(const void* g, void* lds) {
  __builtin_amdgcn_global_load_lds(
      (const __attribute__((address_space(1))) void*)g,
      (__attribute__((address_space(3))) void*)lds, 16, 0, 0);
}

// ---------------------------------------------------------------- fused cast kernel
__global__ void cast5_f32_bf16(const float* __restrict__ x, const float* __restrict__ wq,
                               const float* __restrict__ wk, const float* __restrict__ wv,
                               const float* __restrict__ wo,
                               __hip_bfloat16* __restrict__ xb, __hip_bfloat16* __restrict__ wqb,
                               __hip_bfloat16* __restrict__ wkb, __hip_bfloat16* __restrict__ wvb,
                               __hip_bfloat16* __restrict__ wob) {
  const int bid = blockIdx.x;
  const float* src;
  __hip_bfloat16* dst;
  int base;
  if (bid < 16384)      { src = x;  dst = xb;  base = bid; }
  else if (bid < 20480) { src = wq; dst = wqb; base = bid - 16384; }
  else if (bid < 24576) { src = wk; dst = wkb; base = bid - 20480; }
  else if (bid < 28672) { src = wv; dst = wvb; base = bid - 24576; }
  else                  { src = wo; dst = wob; base = bid - 28672; }
  const int i = base * 1024 + threadIdx.x * 4;
  const float4 v = *reinterpret_cast<const float4*>(src + i);
  ushort4_ o = { f2bf(v.x), f2bf(v.y), f2bf(v.z), f2bf(v.w) };
  *reinterpret_cast<ushort4_*>(dst + i) = o;
}

// ---------------------------------------------------------------- GEMM: 256x256 tile, BK=32
// Phase-split schedule, 4-slot LDS ring, prefetch distance 3, counted vmcnt (never 0 in loop).
// Publication ledger (per wave, 4 gl_lds ops/tile):
//   prologue: tiles 0..2 staged (12 ops) -> vmcnt(8)+barrier retires tile 0 (both halves).
//   iter kt ph1: vmcnt(8) retires through tile kt+1 -> iter kt+1 reads are safe.
//   tail: vmcnt(4) -> tile nkt-2; vmcnt(0) -> tile nkt-1.
//   WAR: stage(kt+3) -> slot (kt-1)&3 issues after iter kt-1's final barrier, by which
//   every wave's reads of that slot have drained (lgkmcnt before its MFMAs).
template <int MODE>
__global__ __launch_bounds__(512, 2)
void gemm256p(const __hip_bfloat16* __restrict__ Ap, const __hip_bfloat16* __restrict__ Bp,
              const float* __restrict__ bias, void* __restrict__ Cout,
              int M, int N, int K) {
  __shared__ __align__(16) __hip_bfloat16 SA[4][256 * 32];
  __shared__ __align__(16) __hip_bfloat16 SB[4][256 * 32];

  const int tid = threadIdx.x;
  const int wid = tid >> 6, lane = tid & 63;
  const int wr = wid >> 2, wc = wid & 3;
  const int g = lane >> 4, c16 = lane & 15;

  const int nbn = N >> 8;
  const int cpx = gridDim.x >> 3;
  const int swzb = (blockIdx.x & 7) * cpx + (blockIdx.x >> 3);
  const int bm = swzb / nbn, bn = swzb % nbn;

  const int srow = lane >> 2;                       // staging row within 16-row slice
  const int slog = (lane & 3) ^ ((lane >> 3) & 3);  // inverse-swizzled source slot
  const int swz = c16 * 32 + (g ^ ((c16 >> 1) & 3)) * 8;  // swizzled read offset

  floatx4 acc[8][4] = {};
  short8 afA[4], afB[4], bf[4];

  auto stage_i = [&](int kt, int i) {               // one pair: A-gload + B-gload
    const int kb = kt * 32;
    const int slot = kt & 3;
    const int rbase = i * 128 + wid * 16;
    gl_lds16(Ap + (size_t)(bm * 256 + rbase + srow) * K + kb + slog * 8,
             SA[slot] + rbase * 32);
    gl_lds16(Bp + (size_t)(bn * 256 + rbase + srow) * K + kb + slog * 8,
             SB[slot] + rbase * 32);
  };

  auto readA = [&](int slot, int half, short8* af) {
    const __hip_bfloat16* sa = SA[slot];
#pragma unroll
    for (int m = 0; m < 4; ++m)
      af[m] = *reinterpret_cast<const short8*>(sa + wr * 4096 + (half * 4 + m) * 512 + swz);
  };
  auto readB = [&](int slot) {
    const __hip_bfloat16* sb = SB[slot];
#pragma unroll
    for (int n = 0; n < 4; ++n)
      bf[n] = *reinterpret_cast<const short8*>(sb + wc * 2048 + n * 512 + swz);
  };
  auto mfma16 = [&](short8* af, int mh) {
    __builtin_amdgcn_s_setprio(1);
#pragma unroll
    for (int m = 0; m < 4; ++m)
#pragma unroll
      for (int n = 0; n < 4; ++n)
        acc[mh * 4 + m][n] = MFMA16(af[m], bf[n], acc[mh * 4 + m][n]);
    __builtin_amdgcn_s_setprio(0);
  };

  const int nkt = K >> 5;                           // 64 K-tiles
  // prologue: 3 tiles in flight (12 gl_lds ops/wave)
  stage_i(0, 0); stage_i(0, 1);
  stage_i(1, 0); stage_i(1, 1);
  stage_i(2, 0); stage_i(2, 1);
  // DRAIN tile 0 before first reads (this was the round-8 race)
  asm volatile("s_waitcnt vmcnt(8)" ::: "memory");
  __builtin_amdgcn_s_barrier();

  for (int kt = 0; kt < nkt - 3; ++kt) {
    const int s = kt & 3;
    // ---- phase 0
    readA(s, 0, afA);
    readB(s);
    stage_i(kt + 3, 0);
    asm volatile("" ::: "memory");
    __builtin_amdgcn_s_barrier();
    mfma16(afA, 0);
    asm volatile("" ::: "memory");
    __builtin_amdgcn_s_barrier();
    // ---- phase 1
    readA(s, 1, afB);
    stage_i(kt + 3, 1);
    asm volatile("s_waitcnt vmcnt(8)" ::: "memory");   // retires through tile kt+1
    __builtin_amdgcn_s_barrier();
    mfma16(afB, 1);
    asm volatile("" ::: "memory");
    __builtin_amdgcn_s_barrier();
  }
  // ---- peeled tail: tiles nkt-3, nkt-2, nkt-1 (no staging; drain 8 -> 4 -> 0)
#pragma unroll
  for (int t = 0; t < 3; ++t) {
    const int kt = nkt - 3 + t;
    const int s = kt & 3;
    readA(s, 0, afA);
    readB(s);
    asm volatile("" ::: "memory");
    __builtin_amdgcn_s_barrier();
    mfma16(afA, 0);
    asm volatile("" ::: "memory");
    __builtin_amdgcn_s_barrier();
    readA(s, 1, afB);
    if (t == 0) asm volatile("s_waitcnt vmcnt(4)" ::: "memory");
    else if (t == 1) asm volatile("s_waitcnt vmcnt(0)" ::: "memory");
    __builtin_amdgcn_s_barrier();
    mfma16(afB, 1);
    asm volatile("" ::: "memory");
    __builtin_amdgcn_s_barrier();
  }

  // ---- epilogue
#pragma unroll
  for (int n = 0; n < 4; ++n) {
    const int colg = bn * 256 + wc * 64 + n * 16 + c16;
    const float bv = bias[colg];
#pragma unroll
    for (int m = 0; m < 8; ++m) {
      const int rowg = bm * 256 + wr * 128 + m * 16 + g * 4;
      if (MODE == 0) {
        __hip_bfloat16* C = (__hip_bfloat16*)Cout;
#pragma unroll
        for (int j = 0; j < 4; ++j)
          C[(size_t)(rowg + j) * N + colg] = __float2bfloat16(acc[m][n][j] + bv);
      } else if (MODE == 1) {
        __hip_bfloat16* C = (__hip_bfloat16*)Cout;
        const int bb = rowg >> 11, t0 = rowg & 2047;
        ushort4_ pk = { f2bf(acc[m][n][0] + bv), f2bf(acc[m][n][1] + bv),
                        f2bf(acc[m][n][2] + bv), f2bf(acc[m][n][3] + bv) };
        *reinterpret_cast<ushort4_*>(C + ((size_t)bb * 2048 + colg) * 2048 + t0) = pk;
      } else {
        float* C = (float*)Cout;
#pragma unroll
        for (int j = 0; j < 4; ++j)
          C[(size_t)(rowg + j) * N + colg] = acc[m][n][j] + bv;
      }
    }
  }
}

// ---------------------------------------------------------------- flash attention v4b (causal)
// Proven structure (LB(256,2), VGPR ~108) + exp2-domain softmax.
// Swapped-operand: QK^T as MFMA(K,Q) -> S^T (col=q=c16), PV as MFMA(V,P) -> O^T.
__global__ __launch_bounds__(256, 2)
void attn_fwd4(const __hip_bfloat16* __restrict__ Q, const __hip_bfloat16* __restrict__ K,
               const __hip_bfloat16* __restrict__ Vt, __hip_bfloat16* __restrict__ ctx) {
  constexpr int T = 2048, C = 2048, D = 128;
  __shared__ __align__(16) __hip_bfloat16 Ks[64][136];
  __shared__ __align__(16) __hip_bfloat16 Vs[128][64];
  __shared__ __align__(16) __hip_bfloat16 Pl[4][32][64];

  const int tid = threadIdx.x;
  const int w = tid >> 6, lane = tid & 63;
  const int g = lane >> 4, c16 = lane & 15;

  const int bid = blockIdx.x;
  const int swz = (bid & 7) * 128 + (bid >> 3);
  const int bh = swz >> 4, qb = 15 - (swz & 15);
  const int b = bh >> 4, h = bh & 15;
  const int wq = qb * 128 + w * 32;

  const __hip_bfloat16* Qh = Q + (size_t)b * T * C + h * D;
  const __hip_bfloat16* Kh = K + (size_t)b * T * C + h * D;
  const __hip_bfloat16* Vh = Vt + (size_t)bh * D * T;

  short8 qf[2][4];
#pragma unroll
  for (int m = 0; m < 2; ++m)
#pragma unroll
    for (int kk = 0; kk < 4; ++kk)
      qf[m][kk] = *reinterpret_cast<const short8*>(Qh + (size_t)(wq + m * 16 + c16) * C + kk * 32 + g * 8);

  floatx4 acc[2][8] = {};
  float mrow[2] = {-INFINITY, -INFINITY};
  float lrow[2] = {0.f, 0.f};

  const float scale2 = 0.12751744f;     // log2(e) / sqrt(128) -> exp2 domain
  const int krow = tid >> 4, kcol = (tid & 15) * 8;
  const int vrow = tid >> 3;
  const int vslot = (tid & 7) ^ (vrow & 7);
  const int vgcol = (tid & 7) * 8;

  short8 kr[4], vr[4];
  auto gloadK = [&](int kb) {
#pragma unroll
    for (int p = 0; p < 4; ++p)
      kr[p] = *reinterpret_cast<const short8*>(Kh + (size_t)(kb + p * 16 + krow) * C + kcol);
  };
  auto gloadV = [&](int kb) {
#pragma unroll
    for (int p = 0; p < 4; ++p)
      vr[p] = *reinterpret_cast<const short8*>(Vh + (size_t)(p * 32 + vrow) * T + kb + vgcol);
  };

  __hip_bfloat16 (*Pq)[64] = Pl[w];
  const int nkt = qb * 2 + 2;
  gloadK(0);
  gloadV(0);

  for (int kt = 0; kt < nkt; ++kt) {
    const int kb = kt * 64;
    __syncthreads();
#pragma unroll
    for (int p = 0; p < 4; ++p)
      *reinterpret_cast<short8*>(&Ks[p * 16 + krow][kcol]) = kr[p];
#pragma unroll
    for (int p = 0; p < 4; ++p)
      *reinterpret_cast<short8*>(&Vs[p * 32 + vrow][vslot * 8]) = vr[p];
    __syncthreads();

    const bool hasnext = (kt + 1 < nkt);
    const bool part = (kb <= wq + 31);
    if (hasnext) gloadK(kb + 64);

    if (part) {
      const bool needmask = (kb + 63 > wq);
      floatx4 s[2][4] = {};
      __builtin_amdgcn_s_setprio(1);
#pragma unroll
      for (int n = 0; n < 4; ++n)
#pragma unroll
        for (int kk = 0; kk < 4; ++kk) {
          short8 kf = *reinterpret_cast<const short8*>(&Ks[n * 16 + c16][kk * 32 + g * 8]);
          s[0][n] = MFMA16(kf, qf[0][kk], s[0][n]);
          s[1][n] = MFMA16(kf, qf[1][kk], s[1][n]);
        }
      __builtin_amdgcn_s_setprio(0);
      float vmax[2];
#pragma unroll
      for (int m = 0; m < 2; ++m) {
        const int q = wq + m * 16 + c16;
        float vm = -INFINITY;
#pragma unroll
        for (int n = 0; n < 4; ++n)
#pragma unroll
          for (int j = 0; j < 4; ++j) {
            float a = s[m][n][j] * scale2;
            if (needmask && (kb + n * 16 + g * 4 + j > q)) a = -INFINITY;
            s[m][n][j] = a;
            vm = fmaxf(vm, a);
          }
        vm = fmaxf(vm, __shfl_xor(vm, 16));
        vm = fmaxf(vm, __shfl_xor(vm, 32));
        vmax[m] = vm;
      }
      const float grow = fmaxf(vmax[0] - mrow[0], vmax[1] - mrow[1]);
      const bool nore = __all(grow <= 8.0f);
#pragma unroll
      for (int m = 0; m < 2; ++m) {
        const float mn = nore ? mrow[m] : fmaxf(mrow[m], vmax[m]);
        float rs = 0.f;
#pragma unroll
        for (int n = 0; n < 4; ++n) {
          float p0 = exp2f(s[m][n][0] - mn), p1 = exp2f(s[m][n][1] - mn);
          float p2 = exp2f(s[m][n][2] - mn), p3 = exp2f(s[m][n][3] - mn);
          rs += (p0 + p1) + (p2 + p3);
          ushort4_ pk = { f2bf(p0), f2bf(p1), f2bf(p2), f2bf(p3) };
          *reinterpret_cast<ushort4_*>(&Pq[m * 16 + c16][((4 * n + g) ^ c16) * 4]) = pk;
        }
        rs += __shfl_xor(rs, 16);
        rs += __shfl_xor(rs, 32);
        if (nore) {
          lrow[m] += rs;
        } else {
          const float sc = exp2f(mrow[m] - mn);
          lrow[m] = lrow[m] * sc + rs;
          mrow[m] = mn;
#pragma unroll
          for (int dt = 0; dt < 8; ++dt)
#pragma unroll
            for (int j = 0; j < 4; ++j) acc[m][dt][j] *= sc;
        }
      }
    }
    if (hasnext) gloadV(kb + 64);
    if (part) {
      short8 pb[2][2];
#pragma unroll
      for (int m = 0; m < 2; ++m)
#pragma unroll
        for (int ks = 0; ks < 2; ++ks) {
          short4_ lo = *reinterpret_cast<const short4_*>(&Pq[m * 16 + c16][((8 * ks + 2 * g) ^ c16) * 4]);
          short4_ hi = *reinterpret_cast<const short4_*>(&Pq[m * 16 + c16][((8 * ks + 2 * g + 1) ^ c16) * 4]);
          short8 r;
          r[0] = lo[0]; r[1] = lo[1]; r[2] = lo[2]; r[3] = lo[3];
          r[4] = hi[0]; r[5] = hi[1]; r[6] = hi[2]; r[7] = hi[3];
          pb[m][ks] = r;
        }
      __builtin_amdgcn_s_setprio(1);
#pragma unroll
      for (int dt = 0; dt < 8; ++dt)
#pragma unroll
        for (int ks = 0; ks < 2; ++ks) {
          const int pslot = ((ks * 4 + g) ^ (c16 & 7)) * 8;
          short8 vf = *reinterpret_cast<const short8*>(&Vs[dt * 16 + c16][pslot]);
          acc[0][dt] = MFMA16(vf, pb[0][ks], acc[0][dt]);
          acc[1][dt] = MFMA16(vf, pb[1][ks], acc[1][dt]);
        }
      __builtin_amdgcn_s_setprio(0);
    }
  }

#pragma unroll
  for (int m = 0; m < 2; ++m) {
    const float inv = 1.0f / lrow[m];
    const size_t row = (size_t)b * T + wq + m * 16 + c16;
#pragma unroll
    for (int dt = 0; dt < 8; ++dt) {
      ushort4_ o = { f2bf(acc[m][dt][0] * inv), f2bf(acc[m][dt][1] * inv),
                     f2bf(acc[m][dt][2] * inv), f2bf(acc[m][dt][3] * inv) };
      *reinterpret_cast<ushort4_*>(ctx + row * C + h * D + dt * 16 + g * 4) = o;
    }
  }
}

// ---------------------------------------------------------------- launch
extern "C" void kernel_launch(void* const* d_in, const int* in_sizes, int n_in,
                              void* d_out, int out_size, void* d_ws, size_t ws_size,
                              hipStream_t stream) {
  const float* x  = (const float*)d_in[0];
  const float* Wq = (const float*)d_in[1];
  const float* bq = (const float*)d_in[2];
  const float* Wk = (const float*)d_in[3];
  const float* bk = (const float*)d_in[4];
  const float* Wv = (const float*)d_in[5];
  const float* bv = (const float*)d_in[6];
  const float* Wo = (const float*)d_in[7];
  const float* bo = (const float*)d_in[8];

  const int M = 8192, N = 2048, K = 2048;
  const size_t MB = 1u << 20;
  char* ws = (char*)d_ws;
  __hip_bfloat16* xb  = (__hip_bfloat16*)(ws);
  __hip_bfloat16* wqb = (__hip_bfloat16*)(ws + 32 * MB);
  __hip_bfloat16* wkb = (__hip_bfloat16*)(ws + 40 * MB);
  __hip_bfloat16* wvb = (__hip_bfloat16*)(ws + 48 * MB);
  __hip_bfloat16* wob = (__hip_bfloat16*)(ws + 56 * MB);
  __hip_bfloat16* Qb  = (__hip_bfloat16*)(ws + 64 * MB);
  __hip_bfloat16* Kb  = (__hip_bfloat16*)(ws + 96 * MB);
  __hip_bfloat16* Vtb = (__hip_bfloat16*)(ws + 128 * MB);
  if (ws_size < 160 * MB) return;

  cast5_f32_bf16<<<32768, 256, 0, stream>>>(x, Wq, Wk, Wv, Wo, xb, wqb, wkb, wvb, wob);

  const dim3 gg((M / 256) * (N / 256));   // 256 blocks = 1 per CU
  gemm256p<0><<<gg, 512, 0, stream>>>(xb, wqb, bq, Qb, M, N, K);
  gemm256p<0><<<gg, 512, 0, stream>>>(xb, wkb, bk, Kb, M, N, K);
  gemm256p<1><<<gg, 512, 0, stream>>>(xb, wvb, bv, Vtb, M, N, K);

  attn_fwd4<<<64 * 16, 256, 0, stream>>>(Qb, Kb, Vtb, xb);

  gemm256p<2><<<gg, 512, 0, stream>>>(xb, wob, bo, d_out, M, N, K);
}

// Round 10
// 471.519 us; speedup vs baseline: 1.9572x; 1.0620x over previous
//
#include <hip/hip_runtime.h>
#include <hip/hip_bf16.h>
#include <cstdint>
#include <cstddef>

typedef __attribute__((ext_vector_type(8))) short short8;
typedef __attribute__((ext_vector_type(4))) short short4_;
typedef __attribute__((ext_vector_type(4))) float floatx4;
typedef __attribute__((ext_vector_type(4))) unsigned short ushort4_;

#define MFMA16(a, b, c) __builtin_amdgcn_mfma_f32_16x16x32_bf16((a), (b), (c), 0, 0, 0)

__device__ __forceinline__ unsigned short f2bf(float f) {
  __hip_bfloat16 h = __float2bfloat16(f);
  return *reinterpret_cast<unsigned short*>(&h);
}

__device__ __forceinline__ void gl_lds16(const void* g, void* lds) {
  __builtin_amdgcn_global_load_lds(
      (const __attribute__((address_space(1))) void*)g,
      (__attribute__((address_space(3))) void*)lds, 16, 0, 0);
}

// ---------------------------------------------------------------- fused cast kernel
__global__ void cast5_f32_bf16(const float* __restrict__ x, const float* __restrict__ wq,
                               const float* __restrict__ wk, const float* __restrict__ wv,
                               const float* __restrict__ wo,
                               __hip_bfloat16* __restrict__ xb, __hip_bfloat16* __restrict__ wqb,
                               __hip_bfloat16* __restrict__ wkb, __hip_bfloat16* __restrict__ wvb,
                               __hip_bfloat16* __restrict__ wob) {
  const int bid = blockIdx.x;
  const float* src;
  __hip_bfloat16* dst;
  int base;
  if (bid < 16384)      { src = x;  dst = xb;  base = bid; }
  else if (bid < 20480) { src = wq; dst = wqb; base = bid - 16384; }
  else if (bid < 24576) { src = wk; dst = wkb; base = bid - 20480; }
  else if (bid < 28672) { src = wv; dst = wvb; base = bid - 24576; }
  else                  { src = wo; dst = wob; base = bid - 28672; }
  const int i = base * 1024 + threadIdx.x * 4;
  const float4 v = *reinterpret_cast<const float4*>(src + i);
  ushort4_ o = { f2bf(v.x), f2bf(v.y), f2bf(v.z), f2bf(v.w) };
  *reinterpret_cast<ushort4_*>(dst + i) = o;
}

// ---------------------------------------------------------------- GEMM: 256x256 tile, BK=32
// Phase-split schedule, 4-slot LDS ring, prefetch distance 3, counted vmcnt (never 0 in loop).
template <int MODE>
__global__ __launch_bounds__(512, 2)
void gemm256p(const __hip_bfloat16* __restrict__ Ap, const __hip_bfloat16* __restrict__ Bp,
              const float* __restrict__ bias, void* __restrict__ Cout,
              int M, int N, int K) {
  __shared__ __align__(16) __hip_bfloat16 SA[4][256 * 32];
  __shared__ __align__(16) __hip_bfloat16 SB[4][256 * 32];

  const int tid = threadIdx.x;
  const int wid = tid >> 6, lane = tid & 63;
  const int wr = wid >> 2, wc = wid & 3;
  const int g = lane >> 4, c16 = lane & 15;

  const int nbn = N >> 8;
  const int cpx = gridDim.x >> 3;
  const int swzb = (blockIdx.x & 7) * cpx + (blockIdx.x >> 3);
  const int bm = swzb / nbn, bn = swzb % nbn;

  const int srow = lane >> 2;
  const int slog = (lane & 3) ^ ((lane >> 3) & 3);
  const int swz = c16 * 32 + (g ^ ((c16 >> 1) & 3)) * 8;

  floatx4 acc[8][4] = {};
  short8 afA[4], afB[4], bf[4];

  auto stage_i = [&](int kt, int i) {
    const int kb = kt * 32;
    const int slot = kt & 3;
    const int rbase = i * 128 + wid * 16;
    gl_lds16(Ap + (size_t)(bm * 256 + rbase + srow) * K + kb + slog * 8,
             SA[slot] + rbase * 32);
    gl_lds16(Bp + (size_t)(bn * 256 + rbase + srow) * K + kb + slog * 8,
             SB[slot] + rbase * 32);
  };

  auto readA = [&](int slot, int half, short8* af) {
    const __hip_bfloat16* sa = SA[slot];
#pragma unroll
    for (int m = 0; m < 4; ++m)
      af[m] = *reinterpret_cast<const short8*>(sa + wr * 4096 + (half * 4 + m) * 512 + swz);
  };
  auto readB = [&](int slot) {
    const __hip_bfloat16* sb = SB[slot];
#pragma unroll
    for (int n = 0; n < 4; ++n)
      bf[n] = *reinterpret_cast<const short8*>(sb + wc * 2048 + n * 512 + swz);
  };
  auto mfma16 = [&](short8* af, int mh) {
    __builtin_amdgcn_s_setprio(1);
#pragma unroll
    for (int m = 0; m < 4; ++m)
#pragma unroll
      for (int n = 0; n < 4; ++n)
        acc[mh * 4 + m][n] = MFMA16(af[m], bf[n], acc[mh * 4 + m][n]);
    __builtin_amdgcn_s_setprio(0);
  };

  const int nkt = K >> 5;
  stage_i(0, 0); stage_i(0, 1);
  stage_i(1, 0); stage_i(1, 1);
  stage_i(2, 0); stage_i(2, 1);
  asm volatile("s_waitcnt vmcnt(8)" ::: "memory");   // drain tile 0
  __builtin_amdgcn_s_barrier();

  for (int kt = 0; kt < nkt - 3; ++kt) {
    const int s = kt & 3;
    readA(s, 0, afA);
    readB(s);
    stage_i(kt + 3, 0);
    asm volatile("" ::: "memory");
    __builtin_amdgcn_s_barrier();
    mfma16(afA, 0);
    asm volatile("" ::: "memory");
    __builtin_amdgcn_s_barrier();
    readA(s, 1, afB);
    stage_i(kt + 3, 1);
    asm volatile("s_waitcnt vmcnt(8)" ::: "memory");
    __builtin_amdgcn_s_barrier();
    mfma16(afB, 1);
    asm volatile("" ::: "memory");
    __builtin_amdgcn_s_barrier();
  }
#pragma unroll
  for (int t = 0; t < 3; ++t) {
    const int kt = nkt - 3 + t;
    const int s = kt & 3;
    readA(s, 0, afA);
    readB(s);
    asm volatile("" ::: "memory");
    __builtin_amdgcn_s_barrier();
    mfma16(afA, 0);
    asm volatile("" ::: "memory");
    __builtin_amdgcn_s_barrier();
    readA(s, 1, afB);
    if (t == 0) asm volatile("s_waitcnt vmcnt(4)" ::: "memory");
    else if (t == 1) asm volatile("s_waitcnt vmcnt(0)" ::: "memory");
    __builtin_amdgcn_s_barrier();
    mfma16(afB, 1);
    asm volatile("" ::: "memory");
    __builtin_amdgcn_s_barrier();
  }

#pragma unroll
  for (int n = 0; n < 4; ++n) {
    const int colg = bn * 256 + wc * 64 + n * 16 + c16;
    const float bv = bias[colg];
#pragma unroll
    for (int m = 0; m < 8; ++m) {
      const int rowg = bm * 256 + wr * 128 + m * 16 + g * 4;
      if (MODE == 0) {
        __hip_bfloat16* C = (__hip_bfloat16*)Cout;
#pragma unroll
        for (int j = 0; j < 4; ++j)
          C[(size_t)(rowg + j) * N + colg] = __float2bfloat16(acc[m][n][j] + bv);
      } else if (MODE == 1) {
        __hip_bfloat16* C = (__hip_bfloat16*)Cout;
        const int bb = rowg >> 11, t0 = rowg & 2047;
        ushort4_ pk = { f2bf(acc[m][n][0] + bv), f2bf(acc[m][n][1] + bv),
                        f2bf(acc[m][n][2] + bv), f2bf(acc[m][n][3] + bv) };
        *reinterpret_cast<ushort4_*>(C + ((size_t)bb * 2048 + colg) * 2048 + t0) = pk;
      } else {
        float* C = (float*)Cout;
#pragma unroll
        for (int j = 0; j < 4; ++j)
          C[(size_t)(rowg + j) * N + colg] = acc[m][n][j] + bv;
      }
    }
  }
}

// ---------------------------------------------------------------- flash attention v6 (causal)
// v4b swapped-operand structure (LB(256,2), ~112 VGPR) + 40960 B LDS -> 4 blocks/CU:
//   Ks[64*128] slot-XOR (^row&7), Vs[128*64] slot-XOR, Pl[4][16*64] m-sequenced.
// All three layouts verified correct on HW (rounds 4/5/6/9). __expf softmax.
__global__ __launch_bounds__(256, 2)
void attn_fwd6(const __hip_bfloat16* __restrict__ Q, const __hip_bfloat16* __restrict__ K,
               const __hip_bfloat16* __restrict__ Vt, __hip_bfloat16* __restrict__ ctx) {
  constexpr int T = 2048, C = 2048, D = 128;
  __shared__ __align__(16) __hip_bfloat16 Ks[64 * 128];    // 16 KB
  __shared__ __align__(16) __hip_bfloat16 Vs[128 * 64];    // 16 KB
  __shared__ __align__(16) __hip_bfloat16 Pl[4][16 * 64];  //  8 KB
  // total 40960 B -> 4 blocks/CU

  const int tid = threadIdx.x;
  const int w = tid >> 6, lane = tid & 63;
  const int g = lane >> 4, c16 = lane & 15;

  const int bid = blockIdx.x;
  const int swz = (bid & 7) * 128 + (bid >> 3);
  const int bh = swz >> 4, qb = 15 - (swz & 15);
  const int b = bh >> 4, h = bh & 15;
  const int wq = qb * 128 + w * 32;

  const __hip_bfloat16* Qh = Q + (size_t)b * T * C + h * D;
  const __hip_bfloat16* Kh = K + (size_t)b * T * C + h * D;
  const __hip_bfloat16* Vh = Vt + (size_t)bh * D * T;

  short8 qf[2][4];
#pragma unroll
  for (int m = 0; m < 2; ++m)
#pragma unroll
    for (int kk = 0; kk < 4; ++kk)
      qf[m][kk] = *reinterpret_cast<const short8*>(Qh + (size_t)(wq + m * 16 + c16) * C + kk * 32 + g * 8);

  floatx4 acc[2][8] = {};
  float mrow[2] = {-INFINITY, -INFINITY};
  float lrow[2] = {0.f, 0.f};

  const float scale = 0.08838834764831845f;   // 1/sqrt(128)
  const int krow = tid >> 4;                  // K staging row within 16-row chunk
  const int kslot = (tid & 15) ^ (krow & 7);  // XOR'd 16B slot
  const int kgcol = (tid & 15) * 8;
  const int vrow = tid >> 3;
  const int vslot = (tid & 7) ^ (vrow & 7);
  const int vgcol = (tid & 7) * 8;

  short8 kr[4], vr[4];
  auto gloadK = [&](int kb) {
#pragma unroll
    for (int p = 0; p < 4; ++p)
      kr[p] = *reinterpret_cast<const short8*>(Kh + (size_t)(kb + p * 16 + krow) * C + kgcol);
  };
  auto gloadV = [&](int kb) {
#pragma unroll
    for (int p = 0; p < 4; ++p)
      vr[p] = *reinterpret_cast<const short8*>(Vh + (size_t)(p * 32 + vrow) * T + kb + vgcol);
  };

  __hip_bfloat16* Pq = Pl[w];
  const int nkt = qb * 2 + 2;
  gloadK(0);
  gloadV(0);

  for (int kt = 0; kt < nkt; ++kt) {
    const int kb = kt * 64;
    __syncthreads();
#pragma unroll
    for (int p = 0; p < 4; ++p)
      *reinterpret_cast<short8*>(&Ks[(p * 16 + krow) * 128 + kslot * 8]) = kr[p];
#pragma unroll
    for (int p = 0; p < 4; ++p)
      *reinterpret_cast<short8*>(&Vs[(p * 32 + vrow) * 64 + vslot * 8]) = vr[p];
    __syncthreads();

    const bool hasnext = (kt + 1 < nkt);
    const bool part = (kb <= wq + 31);
    if (hasnext) gloadK(kb + 64);

    short8 pb[2][2];
    if (part) {
      const bool needmask = (kb + 63 > wq);
      floatx4 s[2][4] = {};
      __builtin_amdgcn_s_setprio(1);
#pragma unroll
      for (int n = 0; n < 4; ++n)
#pragma unroll
        for (int kk = 0; kk < 4; ++kk) {
          short8 kf = *reinterpret_cast<const short8*>(
              &Ks[(n * 16 + c16) * 128 + (((kk * 4 + g) ^ (c16 & 7)) * 8)]);
          s[0][n] = MFMA16(kf, qf[0][kk], s[0][n]);
          s[1][n] = MFMA16(kf, qf[1][kk], s[1][n]);
        }
      __builtin_amdgcn_s_setprio(0);
      float vmax[2];
#pragma unroll
      for (int m = 0; m < 2; ++m) {
        const int q = wq + m * 16 + c16;
        float vm = -INFINITY;
#pragma unroll
        for (int n = 0; n < 4; ++n)
#pragma unroll
          for (int j = 0; j < 4; ++j) {
            float a = s[m][n][j] * scale;
            if (needmask && (kb + n * 16 + g * 4 + j > q)) a = -INFINITY;
            s[m][n][j] = a;
            vm = fmaxf(vm, a);
          }
        vm = fmaxf(vm, __shfl_xor(vm, 16));
        vm = fmaxf(vm, __shfl_xor(vm, 32));
        vmax[m] = vm;
      }
      const float grow = fmaxf(vmax[0] - mrow[0], vmax[1] - mrow[1]);
      const bool nore = __all(grow <= 8.0f);
#pragma unroll
      for (int m = 0; m < 2; ++m) {
        const float mn = nore ? mrow[m] : fmaxf(mrow[m], vmax[m]);
        float rs = 0.f;
#pragma unroll
        for (int n = 0; n < 4; ++n) {
          float p0 = __expf(s[m][n][0] - mn), p1 = __expf(s[m][n][1] - mn);
          float p2 = __expf(s[m][n][2] - mn), p3 = __expf(s[m][n][3] - mn);
          rs += (p0 + p1) + (p2 + p3);
          ushort4_ pk = { f2bf(p0), f2bf(p1), f2bf(p2), f2bf(p3) };
          *reinterpret_cast<ushort4_*>(&Pq[c16 * 64 + (((4 * n + g) ^ c16) * 4)]) = pk;
        }
        rs += __shfl_xor(rs, 16);
        rs += __shfl_xor(rs, 32);
        if (nore) {
          lrow[m] += rs;
        } else {
          const float sc = __expf(mrow[m] - mn);
          lrow[m] = lrow[m] * sc + rs;
          mrow[m] = mn;
#pragma unroll
          for (int dt = 0; dt < 8; ++dt)
#pragma unroll
            for (int j = 0; j < 4; ++j) acc[m][dt][j] *= sc;
        }
        // read this m's P fragments before m+1 overwrites (DS in-order per wave)
#pragma unroll
        for (int ks = 0; ks < 2; ++ks) {
          short4_ lo = *reinterpret_cast<const short4_*>(&Pq[c16 * 64 + (((8 * ks + 2 * g) ^ c16) * 4)]);
          short4_ hi = *reinterpret_cast<const short4_*>(&Pq[c16 * 64 + (((8 * ks + 2 * g + 1) ^ c16) * 4)]);
          short8 r;
          r[0] = lo[0]; r[1] = lo[1]; r[2] = lo[2]; r[3] = lo[3];
          r[4] = hi[0]; r[5] = hi[1]; r[6] = hi[2]; r[7] = hi[3];
          pb[m][ks] = r;
        }
      }
    }
    if (hasnext) gloadV(kb + 64);
    if (part) {
      __builtin_amdgcn_s_setprio(1);
#pragma unroll
      for (int dt = 0; dt < 8; ++dt)
#pragma unroll
        for (int ks = 0; ks < 2; ++ks) {
          const int pslot = ((ks * 4 + g) ^ (c16 & 7)) * 8;
          short8 vf = *reinterpret_cast<const short8*>(&Vs[(dt * 16 + c16) * 64 + pslot]);
          acc[0][dt] = MFMA16(vf, pb[0][ks], acc[0][dt]);
          acc[1][dt] = MFMA16(vf, pb[1][ks], acc[1][dt]);
        }
      __builtin_amdgcn_s_setprio(0);
    }
  }

#pragma unroll
  for (int m = 0; m < 2; ++m) {
    const float inv = 1.0f / lrow[m];
    const size_t row = (size_t)b * T + wq + m * 16 + c16;
#pragma unroll
    for (int dt = 0; dt < 8; ++dt) {
      ushort4_ o = { f2bf(acc[m][dt][0] * inv), f2bf(acc[m][dt][1] * inv),
                     f2bf(acc[m][dt][2] * inv), f2bf(acc[m][dt][3] * inv) };
      *reinterpret_cast<ushort4_*>(ctx + row * C + h * D + dt * 16 + g * 4) = o;
    }
  }
}

// ---------------------------------------------------------------- launch
extern "C" void kernel_launch(void* const* d_in, const int* in_sizes, int n_in,
                              void* d_out, int out_size, void* d_ws, size_t ws_size,
                              hipStream_t stream) {
  const float* x  = (const float*)d_in[0];
  const float* Wq = (const float*)d_in[1];
  const float* bq = (const float*)d_in[2];
  const float* Wk = (const float*)d_in[3];
  const float* bk = (const float*)d_in[4];
  const float* Wv = (const float*)d_in[5];
  const float* bv = (const float*)d_in[6];
  const float* Wo = (const float*)d_in[7];
  const float* bo = (const float*)d_in[8];

  const int M = 8192, N = 2048, K = 2048;
  const size_t MB = 1u << 20;
  char* ws = (char*)d_ws;
  __hip_bfloat16* xb  = (__hip_bfloat16*)(ws);
  __hip_bfloat16* wqb = (__hip_bfloat16*)(ws + 32 * MB);
  __hip_bfloat16* wkb = (__hip_bfloat16*)(ws + 40 * MB);
  __hip_bfloat16* wvb = (__hip_bfloat16*)(ws + 48 * MB);
  __hip_bfloat16* wob = (__hip_bfloat16*)(ws + 56 * MB);
  __hip_bfloat16* Qb  = (__hip_bfloat16*)(ws + 64 * MB);
  __hip_bfloat16* Kb  = (__hip_bfloat16*)(ws + 96 * MB);
  __hip_bfloat16* Vtb = (__hip_bfloat16*)(ws + 128 * MB);
  if (ws_size < 160 * MB) return;

  cast5_f32_bf16<<<32768, 256, 0, stream>>>(x, Wq, Wk, Wv, Wo, xb, wqb, wkb, wvb, wob);

  const dim3 gg((M / 256) * (N / 256));
  gemm256p<0><<<gg, 512, 0, stream>>>(xb, wqb, bq, Qb, M, N, K);
  gemm256p<0><<<gg, 512, 0, stream>>>(xb, wkb, bk, Kb, M, N, K);
  gemm256p<1><<<gg, 512, 0, stream>>>(xb, wvb, bv, Vtb, M, N, K);

  attn_fwd6<<<64 * 16, 256, 0, stream>>>(Qb, Kb, Vtb, xb);

  gemm256p<2><<<gg, 512, 0, stream>>>(xb, wob, bo, d_out, M, N, K);
}

// Round 11
// 464.972 us; speedup vs baseline: 1.9848x; 1.0141x over previous
//
#include <hip/hip_runtime.h>
#include <hip/hip_bf16.h>
#include <cstdint>
#include <cstddef>

typedef __attribute__((ext_vector_type(8))) short short8;
typedef __attribute__((ext_vector_type(4))) short short4_;
typedef __attribute__((ext_vector_type(4))) float floatx4;
typedef __attribute__((ext_vector_type(4))) unsigned short ushort4_;

#define MFMA16(a, b, c) __builtin_amdgcn_mfma_f32_16x16x32_bf16((a), (b), (c), 0, 0, 0)

__device__ __forceinline__ unsigned short f2bf(float f) {
  __hip_bfloat16 h = __float2bfloat16(f);
  return *reinterpret_cast<unsigned short*>(&h);
}

__device__ __forceinline__ void gl_lds16(const void* g, void* lds) {
  __builtin_amdgcn_global_load_lds(
      (const __attribute__((address_space(1))) void*)g,
      (__attribute__((address_space(3))) void*)lds, 16, 0, 0);
}

// ---------------------------------------------------------------- fused cast kernel
__global__ void cast5_f32_bf16(const float* __restrict__ x, const float* __restrict__ wq,
                               const float* __restrict__ wk, const float* __restrict__ wv,
                               const float* __restrict__ wo,
                               __hip_bfloat16* __restrict__ xb, __hip_bfloat16* __restrict__ wqb,
                               __hip_bfloat16* __restrict__ wkb, __hip_bfloat16* __restrict__ wvb,
                               __hip_bfloat16* __restrict__ wob) {
  const int bid = blockIdx.x;
  const float* src;
  __hip_bfloat16* dst;
  int base;
  if (bid < 16384)      { src = x;  dst = xb;  base = bid; }
  else if (bid < 20480) { src = wq; dst = wqb; base = bid - 16384; }
  else if (bid < 24576) { src = wk; dst = wkb; base = bid - 20480; }
  else if (bid < 28672) { src = wv; dst = wvb; base = bid - 24576; }
  else                  { src = wo; dst = wob; base = bid - 28672; }
  const int i = base * 1024 + threadIdx.x * 4;
  const float4 v = *reinterpret_cast<const float4*>(src + i);
  ushort4_ o = { f2bf(v.x), f2bf(v.y), f2bf(v.z), f2bf(v.w) };
  *reinterpret_cast<ushort4_*>(dst + i) = o;
}

// ---------------------------------------------------------------- GEMM: 256x256 tile, BK=32
// Phase-split schedule, 4-slot LDS ring, prefetch distance 3, counted vmcnt (never 0 in loop).
// Proven: rounds 9/10 (passes, ~65 us/dispatch, 0 bank conflicts).
template <int MODE>
__global__ __launch_bounds__(512, 2)
void gemm256p(const __hip_bfloat16* __restrict__ Ap, const __hip_bfloat16* __restrict__ Bp,
              const float* __restrict__ bias, void* __restrict__ Cout,
              int M, int N, int K) {
  __shared__ __align__(16) __hip_bfloat16 SA[4][256 * 32];
  __shared__ __align__(16) __hip_bfloat16 SB[4][256 * 32];

  const int tid = threadIdx.x;
  const int wid = tid >> 6, lane = tid & 63;
  const int wr = wid >> 2, wc = wid & 3;
  const int g = lane >> 4, c16 = lane & 15;

  const int nbn = N >> 8;
  const int cpx = gridDim.x >> 3;
  const int swzb = (blockIdx.x & 7) * cpx + (blockIdx.x >> 3);
  const int bm = swzb / nbn, bn = swzb % nbn;

  const int srow = lane >> 2;
  const int slog = (lane & 3) ^ ((lane >> 3) & 3);
  const int swz = c16 * 32 + (g ^ ((c16 >> 1) & 3)) * 8;

  floatx4 acc[8][4] = {};
  short8 afA[4], afB[4], bf[4];

  auto stage_i = [&](int kt, int i) {
    const int kb = kt * 32;
    const int slot = kt & 3;
    const int rbase = i * 128 + wid * 16;
    gl_lds16(Ap + (size_t)(bm * 256 + rbase + srow) * K + kb + slog * 8,
             SA[slot] + rbase * 32);
    gl_lds16(Bp + (size_t)(bn * 256 + rbase + srow) * K + kb + slog * 8,
             SB[slot] + rbase * 32);
  };

  auto readA = [&](int slot, int half, short8* af) {
    const __hip_bfloat16* sa = SA[slot];
#pragma unroll
    for (int m = 0; m < 4; ++m)
      af[m] = *reinterpret_cast<const short8*>(sa + wr * 4096 + (half * 4 + m) * 512 + swz);
  };
  auto readB = [&](int slot) {
    const __hip_bfloat16* sb = SB[slot];
#pragma unroll
    for (int n = 0; n < 4; ++n)
      bf[n] = *reinterpret_cast<const short8*>(sb + wc * 2048 + n * 512 + swz);
  };
  auto mfma16 = [&](short8* af, int mh) {
    __builtin_amdgcn_s_setprio(1);
#pragma unroll
    for (int m = 0; m < 4; ++m)
#pragma unroll
      for (int n = 0; n < 4; ++n)
        acc[mh * 4 + m][n] = MFMA16(af[m], bf[n], acc[mh * 4 + m][n]);
    __builtin_amdgcn_s_setprio(0);
  };

  const int nkt = K >> 5;
  stage_i(0, 0); stage_i(0, 1);
  stage_i(1, 0); stage_i(1, 1);
  stage_i(2, 0); stage_i(2, 1);
  asm volatile("s_waitcnt vmcnt(8)" ::: "memory");   // drain tile 0
  __builtin_amdgcn_s_barrier();

  for (int kt = 0; kt < nkt - 3; ++kt) {
    const int s = kt & 3;
    readA(s, 0, afA);
    readB(s);
    stage_i(kt + 3, 0);
    asm volatile("" ::: "memory");
    __builtin_amdgcn_s_barrier();
    mfma16(afA, 0);
    asm volatile("" ::: "memory");
    __builtin_amdgcn_s_barrier();
    readA(s, 1, afB);
    stage_i(kt + 3, 1);
    asm volatile("s_waitcnt vmcnt(8)" ::: "memory");
    __builtin_amdgcn_s_barrier();
    mfma16(afB, 1);
    asm volatile("" ::: "memory");
    __builtin_amdgcn_s_barrier();
  }
#pragma unroll
  for (int t = 0; t < 3; ++t) {
    const int kt = nkt - 3 + t;
    const int s = kt & 3;
    readA(s, 0, afA);
    readB(s);
    asm volatile("" ::: "memory");
    __builtin_amdgcn_s_barrier();
    mfma16(afA, 0);
    asm volatile("" ::: "memory");
    __builtin_amdgcn_s_barrier();
    readA(s, 1, afB);
    if (t == 0) asm volatile("s_waitcnt vmcnt(4)" ::: "memory");
    else if (t == 1) asm volatile("s_waitcnt vmcnt(0)" ::: "memory");
    __builtin_amdgcn_s_barrier();
    mfma16(afB, 1);
    asm volatile("" ::: "memory");
    __builtin_amdgcn_s_barrier();
  }

#pragma unroll
  for (int n = 0; n < 4; ++n) {
    const int colg = bn * 256 + wc * 64 + n * 16 + c16;
    const float bv = bias[colg];
#pragma unroll
    for (int m = 0; m < 8; ++m) {
      const int rowg = bm * 256 + wr * 128 + m * 16 + g * 4;
      if (MODE == 0) {
        __hip_bfloat16* C = (__hip_bfloat16*)Cout;
#pragma unroll
        for (int j = 0; j < 4; ++j)
          C[(size_t)(rowg + j) * N + colg] = __float2bfloat16(acc[m][n][j] + bv);
      } else if (MODE == 1) {
        __hip_bfloat16* C = (__hip_bfloat16*)Cout;
        const int bb = rowg >> 11, t0 = rowg & 2047;
        ushort4_ pk = { f2bf(acc[m][n][0] + bv), f2bf(acc[m][n][1] + bv),
                        f2bf(acc[m][n][2] + bv), f2bf(acc[m][n][3] + bv) };
        *reinterpret_cast<ushort4_*>(C + ((size_t)bb * 2048 + colg) * 2048 + t0) = pk;
      } else {
        float* C = (float*)Cout;
#pragma unroll
        for (int j = 0; j < 4; ++j)
          C[(size_t)(rowg + j) * N + colg] = acc[m][n][j] + bv;
      }
    }
  }
}

// ---------------------------------------------------------------- flash attention v7 (causal)
// = round-10 attn_fwd6 with magic-square load-balanced (head, qb) mapping.
// Every 4-block co-residency group (consecutive OR stride-32 dispatch) sums to the
// ideal 68 k-tile iterations per CU; all 16 q-blocks of a head stay on one XCD.
__global__ __launch_bounds__(256, 2)
void attn_fwd7(const __hip_bfloat16* __restrict__ Q, const __hip_bfloat16* __restrict__ K,
               const __hip_bfloat16* __restrict__ Vt, __hip_bfloat16* __restrict__ ctx) {
  constexpr int T = 2048, C = 2048, D = 128;
  __shared__ __align__(16) __hip_bfloat16 Ks[64 * 128];    // 16 KB, slot^(row&7)
  __shared__ __align__(16) __hip_bfloat16 Vs[128 * 64];    // 16 KB, slot^(row&7)
  __shared__ __align__(16) __hip_bfloat16 Pl[4][16 * 64];  //  8 KB, slot^c16, m-sequenced

  const int tid = threadIdx.x;
  const int w = tid >> 6, lane = tid & 63;
  const int g = lane >> 4, c16 = lane & 15;

  // ---- magic-square balanced mapping
  const int bid = blockIdx.x;
  const int x = bid & 7;              // XCD
  const int i = bid >> 3;             // 0..127 within XCD
  const int lo = i & 3, hi = i >> 5;  // the two 4-block grouping axes
  const int bh = x * 8 + ((i >> 2) & 7);
  // 4x4 magic square (0..15), every row AND column sums to 30 -> 68 tiles per group
  const int qb = (int)((0xF12C4A97865B3DE0ull >> (4 * (hi * 4 + lo))) & 15);
  const int b = bh >> 4, h = bh & 15;
  const int wq = qb * 128 + w * 32;

  const __hip_bfloat16* Qh = Q + (size_t)b * T * C + h * D;
  const __hip_bfloat16* Kh = K + (size_t)b * T * C + h * D;
  const __hip_bfloat16* Vh = Vt + (size_t)bh * D * T;

  short8 qf[2][4];
#pragma unroll
  for (int m = 0; m < 2; ++m)
#pragma unroll
    for (int kk = 0; kk < 4; ++kk)
      qf[m][kk] = *reinterpret_cast<const short8*>(Qh + (size_t)(wq + m * 16 + c16) * C + kk * 32 + g * 8);

  floatx4 acc[2][8] = {};
  float mrow[2] = {-INFINITY, -INFINITY};
  float lrow[2] = {0.f, 0.f};

  const float scale = 0.08838834764831845f;   // 1/sqrt(128)
  const int krow = tid >> 4;
  const int kslot = (tid & 15) ^ (krow & 7);
  const int kgcol = (tid & 15) * 8;
  const int vrow = tid >> 3;
  const int vslot = (tid & 7) ^ (vrow & 7);
  const int vgcol = (tid & 7) * 8;

  short8 kr[4], vr[4];
  auto gloadK = [&](int kb) {
#pragma unroll
    for (int p = 0; p < 4; ++p)
      kr[p] = *reinterpret_cast<const short8*>(Kh + (size_t)(kb + p * 16 + krow) * C + kgcol);
  };
  auto gloadV = [&](int kb) {
#pragma unroll
    for (int p = 0; p < 4; ++p)
      vr[p] = *reinterpret_cast<const short8*>(Vh + (size_t)(p * 32 + vrow) * T + kb + vgcol);
  };

  __hip_bfloat16* Pq = Pl[w];
  const int nkt = qb * 2 + 2;
  gloadK(0);
  gloadV(0);

  for (int kt = 0; kt < nkt; ++kt) {
    const int kb = kt * 64;
    __syncthreads();
#pragma unroll
    for (int p = 0; p < 4; ++p)
      *reinterpret_cast<short8*>(&Ks[(p * 16 + krow) * 128 + kslot * 8]) = kr[p];
#pragma unroll
    for (int p = 0; p < 4; ++p)
      *reinterpret_cast<short8*>(&Vs[(p * 32 + vrow) * 64 + vslot * 8]) = vr[p];
    __syncthreads();

    const bool hasnext = (kt + 1 < nkt);
    const bool part = (kb <= wq + 31);
    if (hasnext) gloadK(kb + 64);

    short8 pb[2][2];
    if (part) {
      const bool needmask = (kb + 63 > wq);
      floatx4 s[2][4] = {};
      __builtin_amdgcn_s_setprio(1);
#pragma unroll
      for (int n = 0; n < 4; ++n)
#pragma unroll
        for (int kk = 0; kk < 4; ++kk) {
          short8 kf = *reinterpret_cast<const short8*>(
              &Ks[(n * 16 + c16) * 128 + (((kk * 4 + g) ^ (c16 & 7)) * 8)]);
          s[0][n] = MFMA16(kf, qf[0][kk], s[0][n]);
          s[1][n] = MFMA16(kf, qf[1][kk], s[1][n]);
        }
      __builtin_amdgcn_s_setprio(0);
      float vmax[2];
#pragma unroll
      for (int m = 0; m < 2; ++m) {
        const int q = wq + m * 16 + c16;
        float vm = -INFINITY;
#pragma unroll
        for (int n = 0; n < 4; ++n)
#pragma unroll
          for (int j = 0; j < 4; ++j) {
            float a = s[m][n][j] * scale;
            if (needmask && (kb + n * 16 + g * 4 + j > q)) a = -INFINITY;
            s[m][n][j] = a;
            vm = fmaxf(vm, a);
          }
        vm = fmaxf(vm, __shfl_xor(vm, 16));
        vm = fmaxf(vm, __shfl_xor(vm, 32));
        vmax[m] = vm;
      }
      const float grow = fmaxf(vmax[0] - mrow[0], vmax[1] - mrow[1]);
      const bool nore = __all(grow <= 8.0f);
#pragma unroll
      for (int m = 0; m < 2; ++m) {
        const float mn = nore ? mrow[m] : fmaxf(mrow[m], vmax[m]);
        float rs = 0.f;
#pragma unroll
        for (int n = 0; n < 4; ++n) {
          float p0 = __expf(s[m][n][0] - mn), p1 = __expf(s[m][n][1] - mn);
          float p2 = __expf(s[m][n][2] - mn), p3 = __expf(s[m][n][3] - mn);
          rs += (p0 + p1) + (p2 + p3);
          ushort4_ pk = { f2bf(p0), f2bf(p1), f2bf(p2), f2bf(p3) };
          *reinterpret_cast<ushort4_*>(&Pq[c16 * 64 + (((4 * n + g) ^ c16) * 4)]) = pk;
        }
        rs += __shfl_xor(rs, 16);
        rs += __shfl_xor(rs, 32);
        if (nore) {
          lrow[m] += rs;
        } else {
          const float sc = __expf(mrow[m] - mn);
          lrow[m] = lrow[m] * sc + rs;
          mrow[m] = mn;
#pragma unroll
          for (int dt = 0; dt < 8; ++dt)
#pragma unroll
            for (int j = 0; j < 4; ++j) acc[m][dt][j] *= sc;
        }
        // read this m's P fragments before m+1 overwrites (DS in-order per wave)
#pragma unroll
        for (int ks = 0; ks < 2; ++ks) {
          short4_ lo2 = *reinterpret_cast<const short4_*>(&Pq[c16 * 64 + (((8 * ks + 2 * g) ^ c16) * 4)]);
          short4_ hi2 = *reinterpret_cast<const short4_*>(&Pq[c16 * 64 + (((8 * ks + 2 * g + 1) ^ c16) * 4)]);
          short8 r;
          r[0] = lo2[0]; r[1] = lo2[1]; r[2] = lo2[2]; r[3] = lo2[3];
          r[4] = hi2[0]; r[5] = hi2[1]; r[6] = hi2[2]; r[7] = hi2[3];
          pb[m][ks] = r;
        }
      }
    }
    if (hasnext) gloadV(kb + 64);
    if (part) {
      __builtin_amdgcn_s_setprio(1);
#pragma unroll
      for (int dt = 0; dt < 8; ++dt)
#pragma unroll
        for (int ks = 0; ks < 2; ++ks) {
          const int pslot = ((ks * 4 + g) ^ (c16 & 7)) * 8;
          short8 vf = *reinterpret_cast<const short8*>(&Vs[(dt * 16 + c16) * 64 + pslot]);
          acc[0][dt] = MFMA16(vf, pb[0][ks], acc[0][dt]);
          acc[1][dt] = MFMA16(vf, pb[1][ks], acc[1][dt]);
        }
      __builtin_amdgcn_s_setprio(0);
    }
  }

#pragma unroll
  for (int m = 0; m < 2; ++m) {
    const float inv = 1.0f / lrow[m];
    const size_t row = (size_t)b * T + wq + m * 16 + c16;
#pragma unroll
    for (int dt = 0; dt < 8; ++dt) {
      ushort4_ o = { f2bf(acc[m][dt][0] * inv), f2bf(acc[m][dt][1] * inv),
                     f2bf(acc[m][dt][2] * inv), f2bf(acc[m][dt][3] * inv) };
      *reinterpret_cast<ushort4_*>(ctx + row * C + h * D + dt * 16 + g * 4) = o;
    }
  }
}

// ---------------------------------------------------------------- launch
extern "C" void kernel_launch(void* const* d_in, const int* in_sizes, int n_in,
                              void* d_out, int out_size, void* d_ws, size_t ws_size,
                              hipStream_t stream) {
  const float* x  = (const float*)d_in[0];
  const float* Wq = (const float*)d_in[1];
  const float* bq = (const float*)d_in[2];
  const float* Wk = (const float*)d_in[3];
  const float* bk = (const float*)d_in[4];
  const float* Wv = (const float*)d_in[5];
  const float* bv = (const float*)d_in[6];
  const float* Wo = (const float*)d_in[7];
  const float* bo = (const float*)d_in[8];

  const int M = 8192, N = 2048, K = 2048;
  const size_t MB = 1u << 20;
  char* ws = (char*)d_ws;
  __hip_bfloat16* xb  = (__hip_bfloat16*)(ws);
  __hip_bfloat16* wqb = (__hip_bfloat16*)(ws + 32 * MB);
  __hip_bfloat16* wkb = (__hip_bfloat16*)(ws + 40 * MB);
  __hip_bfloat16* wvb = (__hip_bfloat16*)(ws + 48 * MB);
  __hip_bfloat16* wob = (__hip_bfloat16*)(ws + 56 * MB);
  __hip_bfloat16* Qb  = (__hip_bfloat16*)(ws + 64 * MB);
  __hip_bfloat16* Kb  = (__hip_bfloat16*)(ws + 96 * MB);
  __hip_bfloat16* Vtb = (__hip_bfloat16*)(ws + 128 * MB);
  if (ws_size < 160 * MB) return;

  cast5_f32_bf16<<<32768, 256, 0, stream>>>(x, Wq, Wk, Wv, Wo, xb, wqb, wkb, wvb, wob);

  const dim3 gg((M / 256) * (N / 256));
  gemm256p<0><<<gg, 512, 0, stream>>>(xb, wqb, bq, Qb, M, N, K);
  gemm256p<0><<<gg, 512, 0, stream>>>(xb, wkb, bk, Kb, M, N, K);
  gemm256p<1><<<gg, 512, 0, stream>>>(xb, wvb, bv, Vtb, M, N, K);

  attn_fwd7<<<64 * 16, 256, 0, stream>>>(Qb, Kb, Vtb, xb);

  gemm256p<2><<<gg, 512, 0, stream>>>(xb, wob, bo, d_out, M, N, K);
}